// Round 3
// baseline (849.143 us; speedup 1.0000x reference)
//
#include <hip/hip_runtime.h>
#include <hip/hip_bf16.h>

// SepConv: relu -> dw3x3 -> pw1x1 -> BN (inference), NHWC fp32 in/out.
// B=16, H=W=224, C=96.
//
// v3: max wave-parallelism + min per-tile overhead.
//  - prep kernel (runs once per iteration, ~3us): pw^T -> bf16 in d_ws,
//    BN folded to scale/shift. Removes ALL per-block pw staging.
//  - main kernel: 12544 blocks x 256 thr = 50176 waves, ONE 16-px tile per
//    wave, no main-loop barriers. LDS only for dwk/dwb (3.9 KB, broadcast
//    reads). __launch_bounds__(256,8) pins VGPR<=64 -> 32 waves/CU.
//  - swapped MFMA operands: D = (pw^T . dw^T) so each lane holds 4
//    consecutive output channels for one pixel -> epilogue is 6 coalesced
//    float4 stores (was 24 scalar stores).
//  - XCD banding: blockIdx&7 owns a contiguous 448-row band (halo L2 reuse).

#define BATCH 16
#define HH 224
#define WWD 224
#define CC 96
#define ROWS (BATCH*HH)            // 3584
#define TPR 14                     // 16-px tiles per row
#define NTILES (ROWS*TPR)          // 50176
#define NTHREADS 256
#define NBLOCKS (NTILES/4)         // 12544 (4 waves/block, 1 tile/wave)
#define BLK_PER_BAND (NBLOCKS/8)   // 1568

typedef __attribute__((ext_vector_type(8))) short short8;
typedef __attribute__((ext_vector_type(4))) float f32x4;

__device__ __forceinline__ unsigned short f2bf(float f){
    union{float f; unsigned u;} v; v.f = f;
    unsigned r = v.u + 0x7fffu + ((v.u >> 16) & 1u);   // RTNE
    return (unsigned short)(r >> 16);
}

// One 3x3 tap: 8 channels for each of the 3 k-steps (24 ch total).
__device__ __forceinline__ void tap_fma(const float* __restrict__ xp,
                                        const float* wp,
                                        float acc[3][8])
{
    #pragma unroll
    for (int ks = 0; ks < 3; ++ks) {
        float4 x0 = *reinterpret_cast<const float4*>(xp + ks*32);
        float4 x1 = *reinterpret_cast<const float4*>(xp + ks*32 + 4);
        float4 w0 = *reinterpret_cast<const float4*>(wp + ks*32);
        float4 w1 = *reinterpret_cast<const float4*>(wp + ks*32 + 4);
        acc[ks][0] += fmaxf(x0.x, 0.f) * w0.x;
        acc[ks][1] += fmaxf(x0.y, 0.f) * w0.y;
        acc[ks][2] += fmaxf(x0.z, 0.f) * w0.z;
        acc[ks][3] += fmaxf(x0.w, 0.f) * w0.w;
        acc[ks][4] += fmaxf(x1.x, 0.f) * w1.x;
        acc[ks][5] += fmaxf(x1.y, 0.f) * w1.y;
        acc[ks][6] += fmaxf(x1.z, 0.f) * w1.z;
        acc[ks][7] += fmaxf(x1.w, 0.f) * w1.w;
    }
}

// ---- prep: pw^T to bf16 + folded BN constants, into workspace ----
__global__ void sepconv_prep(const float* __restrict__ pwk,
                             const float* __restrict__ pwb,
                             const float* __restrict__ gma,
                             const float* __restrict__ bta,
                             const float* __restrict__ mmean,
                             const float* __restrict__ mvar,
                             unsigned short* __restrict__ pwT,
                             float* __restrict__ bnsc,
                             float* __restrict__ bnsh)
{
    int e = blockIdx.x*256 + threadIdx.x;      // grid 36*256 = 9216 exactly
    int ci = e / CC;
    int co = e - ci*CC;
    pwT[co*CC + ci] = f2bf(pwk[e]);
    if (e < CC) {
        float sc = gma[e] / sqrtf(mvar[e] + 1e-3f);
        bnsc[e] = sc;
        bnsh[e] = (pwb[e] - mmean[e]) * sc + bta[e];
    }
}

__global__ __launch_bounds__(NTHREADS, 8) void sepconv_main(
    const float* __restrict__ x,
    const float* __restrict__ dwk,            // (3,3,1,96)
    const float* __restrict__ dwb,            // (96)
    const unsigned short* __restrict__ pwT,   // [co][ci] bf16 (from prep)
    const float* __restrict__ bnsc,
    const float* __restrict__ bnsh,
    float* __restrict__ out)
{
    __shared__ __align__(16) float s_dwk[9][CC];   // 3456 B
    __shared__ __align__(16) float s_dwb[CC];      //  384 B

    const int t = threadIdx.x;
    for (int e = t; e < 9*CC; e += NTHREADS)
        (&s_dwk[0][0])[e] = dwk[e];
    if (t < CC) s_dwb[t] = dwb[t];
    __syncthreads();
    // no barriers below — waves fully independent, 1 tile each

    const int wave = t >> 6;
    const int lane = t & 63;
    const int col  = lane & 15;     // pixel-in-tile (B-operand row / D col)
    const int quad = lane >> 4;     // k-subchunk owner / D row group

    // XCD banding: contiguous 1568-block (448-row) band per XCD slot
    const int xcd = blockIdx.x & 7;
    const int idx = blockIdx.x >> 3;
    const int T   = (xcd*BLK_PER_BAND + idx)*4 + wave;   // 0..50175

    const int rrow = T / TPR;                  // b*224 + h
    const int wt   = T - rrow*TPR;
    const int h    = rrow % HH;
    const int w_me = wt*16 + col;              // this lane's pixel column
    const float* xb = x + (size_t)(rrow*WWD + w_me)*CC + quad*8;

    // ---- depthwise 3x3 (fp32), straight into B-fragment ownership ----
    float acc[3][8];
    #pragma unroll
    for (int ks = 0; ks < 3; ++ks) {
        float4 b0 = *reinterpret_cast<const float4*>(&s_dwb[ks*32 + quad*8]);
        float4 b1 = *reinterpret_cast<const float4*>(&s_dwb[ks*32 + quad*8 + 4]);
        acc[ks][0]=b0.x; acc[ks][1]=b0.y; acc[ks][2]=b0.z; acc[ks][3]=b0.w;
        acc[ks][4]=b1.x; acc[ks][5]=b1.y; acc[ks][6]=b1.z; acc[ks][7]=b1.w;
    }

    #pragma unroll
    for (int kh = -1; kh <= 1; ++kh) {
        const int h2 = h + kh;
        if ((unsigned)h2 >= HH) continue;      // wave-uniform branch
        const float* rp = xb + kh*(WWD*CC);
        const float* wr = &s_dwk[(kh+1)*3][0] + quad*8;
        if (w_me >= 1)       tap_fma(rp - CC, wr,        acc);  // kw=-1
                             tap_fma(rp,      wr + CC,   acc);  // kw= 0
        if (w_me <= WWD-2)   tap_fma(rp + CC, wr + 2*CC, acc);  // kw=+1
    }

    // ---- pack dw result to bf16 B-fragments ----
    short8 bfr[3];
    #pragma unroll
    for (int ks = 0; ks < 3; ++ks) {
        union { short8 v; unsigned u[4]; } pk;
        #pragma unroll
        for (int j = 0; j < 4; ++j)
            pk.u[j] = (unsigned)f2bf(acc[ks][2*j])
                    | ((unsigned)f2bf(acc[ks][2*j+1]) << 16);
        bfr[ks] = pk.v;
    }

    // ---- pointwise via MFMA (swapped operands: D[co][px]) + BN + store ----
    // A-frag (pw): lane holds co = nt*16+col, k = ks*32+quad*8..+7
    // D: lane holds rows co = nt*16 + quad*4 + r, col px = T*16 + (lane&15)
    float* ob = out + (size_t)(T*16 + col)*CC;
    #pragma unroll
    for (int nt = 0; nt < 6; ++nt) {
        f32x4 macc = {0.f, 0.f, 0.f, 0.f};
        #pragma unroll
        for (int ks = 0; ks < 3; ++ks) {
            short8 pfr = *reinterpret_cast<const short8*>(
                pwT + (size_t)(nt*16 + col)*CC + ks*32 + quad*8);
            macc = __builtin_amdgcn_mfma_f32_16x16x32_bf16(pfr, bfr[ks], macc, 0, 0, 0);
        }
        float4 sc4 = *reinterpret_cast<const float4*>(bnsc + nt*16 + quad*4);
        float4 sh4 = *reinterpret_cast<const float4*>(bnsh + nt*16 + quad*4);
        float4 o;
        o.x = macc[0]*sc4.x + sh4.x;
        o.y = macc[1]*sc4.y + sh4.y;
        o.z = macc[2]*sc4.z + sh4.z;
        o.w = macc[3]*sc4.w + sh4.w;
        *reinterpret_cast<float4*>(ob + nt*16 + quad*4) = o;
    }
}

extern "C" void kernel_launch(void* const* d_in, const int* in_sizes, int n_in,
                              void* d_out, int out_size, void* d_ws, size_t ws_size,
                              hipStream_t stream)
{
    unsigned short* pwT = (unsigned short*)d_ws;               // 9216 bf16
    float* bnsc = (float*)((char*)d_ws + 9216*2);              // 96 f32
    float* bnsh = bnsc + CC;                                   // 96 f32

    sepconv_prep<<<36, 256, 0, stream>>>(
        (const float*)d_in[3], (const float*)d_in[4],
        (const float*)d_in[5], (const float*)d_in[6],
        (const float*)d_in[7], (const float*)d_in[8],
        pwT, bnsc, bnsh);

    sepconv_main<<<NBLOCKS, NTHREADS, 0, stream>>>(
        (const float*)d_in[0],
        (const float*)d_in[1],
        (const float*)d_in[2],
        pwT, bnsc, bnsh,
        (float*)d_out);
}

// Round 4
// 793.665 us; speedup vs baseline: 1.0699x; 1.0699x over previous
//
#include <hip/hip_runtime.h>
#include <hip/hip_bf16.h>

// SepConv: relu -> dw3x3 -> pw1x1 -> BN (inference), NHWC fp32 in/out.
// B=16, H=W=224, C=96.
//
// v4 = v3 minus the register spill.
//  - v3 post-mortem: __launch_bounds__(256,8) forced a 64-reg budget; the
//    compiler allocated 32 VGPRs and spilled the dw working set
//    (WRITE_SIZE 307->477 MB = scratch traffic, VALUBusy 15% at 88% occ).
//  - fix 1: __launch_bounds__(256,6) -> 85-VGPR budget, 24 waves/CU (75%).
//  - fix 2: depthwise restructured per-k-step: the 3 MFMA k-chunks are
//    disjoint channel groups, so compute acc[8] for one ks over all 9 taps,
//    pack to bfr[ks], release, next ks. Peak live regs ~halved.
//  - unchanged: prep kernel (pw^T bf16 + folded BN in d_ws), 1 tile/wave,
//    no main-loop barriers, swapped-operand MFMA (coalesced float4 stores),
//    XCD banding.

#define BATCH 16
#define HH 224
#define WWD 224
#define CC 96
#define ROWS (BATCH*HH)            // 3584
#define TPR 14                     // 16-px tiles per row
#define NTILES (ROWS*TPR)          // 50176
#define NTHREADS 256
#define NBLOCKS (NTILES/4)         // 12544 (4 waves/block, 1 tile/wave)
#define BLK_PER_BAND (NBLOCKS/8)   // 1568

typedef __attribute__((ext_vector_type(8))) short short8;
typedef __attribute__((ext_vector_type(4))) float f32x4;

__device__ __forceinline__ unsigned short f2bf(float f){
    union{float f; unsigned u;} v; v.f = f;
    unsigned r = v.u + 0x7fffu + ((v.u >> 16) & 1u);   // RTNE
    return (unsigned short)(r >> 16);
}

// One 3x3 tap, 8 channels of the CURRENT k-step only.
__device__ __forceinline__ void tap8(const float* __restrict__ xp,
                                     const float* wp, float acc[8])
{
    float4 x0 = *reinterpret_cast<const float4*>(xp);
    float4 x1 = *reinterpret_cast<const float4*>(xp + 4);
    float4 w0 = *reinterpret_cast<const float4*>(wp);
    float4 w1 = *reinterpret_cast<const float4*>(wp + 4);
    acc[0] += fmaxf(x0.x, 0.f) * w0.x;
    acc[1] += fmaxf(x0.y, 0.f) * w0.y;
    acc[2] += fmaxf(x0.z, 0.f) * w0.z;
    acc[3] += fmaxf(x0.w, 0.f) * w0.w;
    acc[4] += fmaxf(x1.x, 0.f) * w1.x;
    acc[5] += fmaxf(x1.y, 0.f) * w1.y;
    acc[6] += fmaxf(x1.z, 0.f) * w1.z;
    acc[7] += fmaxf(x1.w, 0.f) * w1.w;
}

// ---- prep: pw^T to bf16 + folded BN constants, into workspace ----
__global__ void sepconv_prep(const float* __restrict__ pwk,
                             const float* __restrict__ pwb,
                             const float* __restrict__ gma,
                             const float* __restrict__ bta,
                             const float* __restrict__ mmean,
                             const float* __restrict__ mvar,
                             unsigned short* __restrict__ pwT,
                             float* __restrict__ bnsc,
                             float* __restrict__ bnsh)
{
    int e = blockIdx.x*256 + threadIdx.x;      // grid 36*256 = 9216 exactly
    int ci = e / CC;
    int co = e - ci*CC;
    pwT[co*CC + ci] = f2bf(pwk[e]);
    if (e < CC) {
        float sc = gma[e] / sqrtf(mvar[e] + 1e-3f);
        bnsc[e] = sc;
        bnsh[e] = (pwb[e] - mmean[e]) * sc + bta[e];
    }
}

__global__ __launch_bounds__(NTHREADS, 6) void sepconv_main(
    const float* __restrict__ x,
    const float* __restrict__ dwk,            // (3,3,1,96)
    const float* __restrict__ dwb,            // (96)
    const unsigned short* __restrict__ pwT,   // [co][ci] bf16 (from prep)
    const float* __restrict__ bnsc,
    const float* __restrict__ bnsh,
    float* __restrict__ out)
{
    __shared__ __align__(16) float s_dwk[9][CC];   // 3456 B
    __shared__ __align__(16) float s_dwb[CC];      //  384 B

    const int t = threadIdx.x;
    for (int e = t; e < 9*CC; e += NTHREADS)
        (&s_dwk[0][0])[e] = dwk[e];
    if (t < CC) s_dwb[t] = dwb[t];
    __syncthreads();
    // no barriers below — waves fully independent, 1 tile each

    const int wave = t >> 6;
    const int lane = t & 63;
    const int col  = lane & 15;     // pixel-in-tile (B-operand row / D col)
    const int quad = lane >> 4;     // k-subchunk owner / D row group

    // XCD banding: contiguous 1568-block (448-row) band per XCD slot
    const int xcd = blockIdx.x & 7;
    const int idx = blockIdx.x >> 3;
    const int T   = (xcd*BLK_PER_BAND + idx)*4 + wave;   // 0..50175

    const int rrow = T / TPR;                  // b*224 + h
    const int wt   = T - rrow*TPR;
    const int h    = rrow % HH;
    const int w_me = wt*16 + col;              // this lane's pixel column
    const float* xb = x + (size_t)(rrow*WWD + w_me)*CC + quad*8;

    const bool wlo = (w_me >= 1);
    const bool whi = (w_me <= WWD-2);

    // ---- depthwise 3x3, one k-step at a time (low register pressure) ----
    short8 bfr[3];
    #pragma unroll
    for (int ks = 0; ks < 3; ++ks) {
        float acc[8];
        {
            float4 b0 = *reinterpret_cast<const float4*>(&s_dwb[ks*32 + quad*8]);
            float4 b1 = *reinterpret_cast<const float4*>(&s_dwb[ks*32 + quad*8 + 4]);
            acc[0]=b0.x; acc[1]=b0.y; acc[2]=b0.z; acc[3]=b0.w;
            acc[4]=b1.x; acc[5]=b1.y; acc[6]=b1.z; acc[7]=b1.w;
        }
        const float* xk = xb + ks*32;
        #pragma unroll
        for (int kh = -1; kh <= 1; ++kh) {
            const int h2 = h + kh;
            if ((unsigned)h2 >= HH) continue;      // wave-uniform branch
            const float* rp = xk + kh*(WWD*CC);
            const float* wr = &s_dwk[(kh+1)*3][0] + ks*32 + quad*8;
            if (wlo) tap8(rp - CC, wr,        acc);  // kw=-1
                     tap8(rp,      wr + CC,   acc);  // kw= 0
            if (whi) tap8(rp + CC, wr + 2*CC, acc);  // kw=+1
        }
        union { short8 v; unsigned u[4]; } pk;
        #pragma unroll
        for (int j = 0; j < 4; ++j)
            pk.u[j] = (unsigned)f2bf(acc[2*j])
                    | ((unsigned)f2bf(acc[2*j+1]) << 16);
        bfr[ks] = pk.v;
    }

    // ---- pointwise via MFMA (swapped operands: D[co][px]) + BN + store ----
    // A-frag (pw): lane holds co = nt*16+col, k = ks*32+quad*8..+7
    // D: lane holds rows co = nt*16 + quad*4 + r, col px = T*16 + (lane&15)
    float* ob = out + (size_t)(T*16 + col)*CC;
    #pragma unroll
    for (int nt = 0; nt < 6; ++nt) {
        f32x4 macc = {0.f, 0.f, 0.f, 0.f};
        #pragma unroll
        for (int ks = 0; ks < 3; ++ks) {
            short8 pfr = *reinterpret_cast<const short8*>(
                pwT + (size_t)(nt*16 + col)*CC + ks*32 + quad*8);
            macc = __builtin_amdgcn_mfma_f32_16x16x32_bf16(pfr, bfr[ks], macc, 0, 0, 0);
        }
        float4 sc4 = *reinterpret_cast<const float4*>(bnsc + nt*16 + quad*4);
        float4 sh4 = *reinterpret_cast<const float4*>(bnsh + nt*16 + quad*4);
        float4 o;
        o.x = macc[0]*sc4.x + sh4.x;
        o.y = macc[1]*sc4.y + sh4.y;
        o.z = macc[2]*sc4.z + sh4.z;
        o.w = macc[3]*sc4.w + sh4.w;
        *reinterpret_cast<float4*>(ob + nt*16 + quad*4) = o;
    }
}

extern "C" void kernel_launch(void* const* d_in, const int* in_sizes, int n_in,
                              void* d_out, int out_size, void* d_ws, size_t ws_size,
                              hipStream_t stream)
{
    unsigned short* pwT = (unsigned short*)d_ws;               // 9216 bf16
    float* bnsc = (float*)((char*)d_ws + 9216*2);              // 96 f32
    float* bnsh = bnsc + CC;                                   // 96 f32

    sepconv_prep<<<36, 256, 0, stream>>>(
        (const float*)d_in[3], (const float*)d_in[4],
        (const float*)d_in[5], (const float*)d_in[6],
        (const float*)d_in[7], (const float*)d_in[8],
        pwT, bnsc, bnsh);

    sepconv_main<<<NBLOCKS, NTHREADS, 0, stream>>>(
        (const float*)d_in[0],
        (const float*)d_in[1],
        (const float*)d_in[2],
        pwT, bnsc, bnsh,
        (float*)d_out);
}